// Round 11
// baseline (156.422 us; speedup 1.0000x reference)
//
#include <hip/hip_runtime.h>
#include <hip/hip_bf16.h>
#include <hip/hip_fp16.h>
#include <cstddef>

#define NN 50000
#define EE 800000
#define SB  196    // ceil(NN/256)
#define GB  782    // ceil(NN/64)
#define ZB  1563   // ceil(8*NN/256)
#define FT  4096   // fused hist||gemm1 grid
#define HBK 3072   // hist-role blocks within FT

typedef _Float16 half4v __attribute__((ext_vector_type(4)));
typedef _Float16 half8v __attribute__((ext_vector_type(8)));
typedef _Float16 h2v    __attribute__((ext_vector_type(2)));
typedef float    f32x4  __attribute__((ext_vector_type(4)));

// ---- init: zero 8 histogram replicas + (last block) cE constants ----
__global__ void init_k(unsigned* __restrict__ dreg,
                       const float* __restrict__ We1, const float* __restrict__ attE1,
                       const float* __restrict__ We2, const float* __restrict__ attE2,
                       float* __restrict__ cE) {
    int t = threadIdx.x;
    if (blockIdx.x == ZB) {
        __shared__ float smc[128];
        if (t < 128) smc[t] = We1[t] * attE1[t];
        __syncthreads();
        for (int off = 32; off; off >>= 1) {
            if (t < 128 && (t & 63) < off) smc[t] += smc[t + off];
            __syncthreads();
        }
        if (t == 0)  cE[0] = smc[0];
        if (t == 64) cE[1] = smc[64];
        __syncthreads();
        if (t < 32) smc[t] = We2[t] * attE2[t];
        __syncthreads();
        for (int off = 16; off; off >>= 1) {
            if (t < off) smc[t] += smc[t + off];
            __syncthreads();
        }
        if (t == 0) cE[2] = smc[0];
        return;
    }
    int i = blockIdx.x * 256 + t;
    if (i < 8 * NN) dreg[i] = 0u;
}

// ---- FUSED hist || gemm1, interleaved roles: (b&3)==3 -> gemm tile b>>2, else hist ----
__global__ __launch_bounds__(256) void histgemm_k(
        const int* __restrict__ ei, unsigned* __restrict__ dreg, int* __restrict__ rank,
        const float* __restrict__ x, const float* __restrict__ W,
        const float* __restrict__ attS, const float* __restrict__ attD,
        __half* __restrict__ h1, float* __restrict__ asrc, float* __restrict__ adst) {
    __shared__ __align__(16) _Float16 xs[64 * 136];
    int t = threadIdx.x;
    int b = blockIdx.x;
    if ((b & 3) != 3) {
        // hist role: hb in [0, HBK)
        int hb = (b >> 2) * 3 + (b & 3);
        for (int e = hb * 256 + t; e < EE; e += HBK * 256) {
            int dst = ei[EE + e];
            int rep = (e >> 8) & 7;                 // pure function of e (scatter recomputes)
            rank[e] = (int)atomicAdd(&dreg[rep * NN + dst], 1u);
        }
        return;
    }
    int tile = b >> 2;
    if (tile >= GB) return;
    int rowbase = tile * 64;
    int wid = t >> 6, lane = t & 63;
    #pragma unroll
    for (int i = 0; i < 8; i++) {
        int idx = t + i * 256;
        int r = idx >> 5;
        int c4 = idx & 31;
        float4 v = make_float4(0.f, 0.f, 0.f, 0.f);
        if (rowbase + r < NN) v = ((const float4*)x)[(size_t)(rowbase + r) * 32 + c4];
        half4v hv = { (_Float16)v.x, (_Float16)v.y, (_Float16)v.z, (_Float16)v.w };
        *(half4v*)&xs[r * 136 + c4 * 4] = hv;
    }
    half8v bf[2][4];
    #pragma unroll
    for (int nt = 0; nt < 2; nt++)
        #pragma unroll
        for (int kk = 0; kk < 4; kk++) {
            int kb = kk * 32 + ((lane >> 4) << 3);
            int c = (wid << 5) + (nt << 4) + (lane & 15);
            half8v f;
            #pragma unroll
            for (int j = 0; j < 8; j++) f[j] = (_Float16)W[(kb + j) * 128 + c];
            bf[nt][kk] = f;
        }
    __syncthreads();
    int ar = lane & 15;
    int ak = (lane >> 4) << 3;
    f32x4 acc[4][2] = {};
    #pragma unroll
    for (int kk = 0; kk < 4; kk++) {
        half8v a[4];
        #pragma unroll
        for (int mt = 0; mt < 4; mt++)
            a[mt] = *(const half8v*)&xs[(mt * 16 + ar) * 136 + kk * 32 + ak];
        #pragma unroll
        for (int mt = 0; mt < 4; mt++)
            #pragma unroll
            for (int nt = 0; nt < 2; nt++)
                acc[mt][nt] = __builtin_amdgcn_mfma_f32_16x16x32_f16(
                    a[mt], bf[nt][kk], acc[mt][nt], 0, 0, 0);
    }
    __syncthreads();
    int drb = (lane >> 4) << 2;
    int dc = (wid << 5) + (lane & 15);
    #pragma unroll
    for (int mt = 0; mt < 4; mt++)
        #pragma unroll
        for (int nt = 0; nt < 2; nt++)
            #pragma unroll
            for (int r = 0; r < 4; r++)
                xs[(mt * 16 + drb + r) * 136 + dc + nt * 16] = (_Float16)acc[mt][nt][r];
    __syncthreads();
    int row = t >> 2;
    int cg = t & 3;
    int grow = rowbase + row;
    float sv = 0.f, dv = 0.f;
    #pragma unroll
    for (int k = 0; k < 4; k++) {
        int c0 = cg * 32 + k * 8;
        half8v hv = *(const half8v*)&xs[row * 136 + c0];
        if (grow < NN) *(half8v*)((_Float16*)h1 + (size_t)grow * 128 + c0) = hv;
        #pragma unroll
        for (int j = 0; j < 8; j++) {
            float f = (float)hv[j];
            sv += f * attS[c0 + j];
            dv += f * attD[c0 + j];
        }
    }
    sv += __shfl_xor(sv, 1);
    dv += __shfl_xor(dv, 1);
    if ((cg & 1) == 0 && grow < NN) {
        asrc[grow * 2 + (cg >> 1)] = sv;
        adst[grow * 2 + (cg >> 1)] = dv;
    }
}

// ---- combine replicas -> deg, per-replica base (ushort), block partial sums ----
__global__ void combine_k(const unsigned* __restrict__ dreg, int* __restrict__ deg,
                          unsigned short* __restrict__ repbase, int* __restrict__ bsum) {
    __shared__ int sm[256];
    int t = threadIdx.x, n = blockIdx.x * 256 + t;
    int d = 0;
    if (n < NN) {
        unsigned base = 0;
        #pragma unroll
        for (int r = 0; r < 8; r++) {
            unsigned c = dreg[r * NN + n];
            repbase[r * NN + n] = (unsigned short)base;
            base += c;
        }
        d = (int)base;
        deg[n] = d;
    }
    sm[t] = d;
    __syncthreads();
    for (int off = 128; off; off >>= 1) {
        if (t < off) sm[t] += sm[t + off];
        __syncthreads();
    }
    if (!t) bsum[blockIdx.x] = sm[0];
}

// ---- scan_final + fold repbase into rowbase8 (saves one random gather in scatter) ----
__global__ void scan_final_k(const int* __restrict__ deg, const int* __restrict__ bsum,
                             const unsigned short* __restrict__ repbase,
                             int* __restrict__ rowptr, int* __restrict__ rowbase8) {
    __shared__ int sm[256];
    __shared__ int boff_s;
    int t = threadIdx.x, b = blockIdx.x, i = b * 256 + t;
    int v0 = (t < b) ? bsum[t] : 0;
    sm[t] = v0;
    __syncthreads();
    for (int off = 128; off; off >>= 1) {
        if (t < off) sm[t] += sm[t + off];
        __syncthreads();
    }
    if (!t) boff_s = sm[0];
    __syncthreads();
    int v = (i < NN) ? deg[i] : 0;
    sm[t] = v;
    __syncthreads();
    for (int off = 1; off < 256; off <<= 1) {
        int a = (t >= off) ? sm[t - off] : 0;
        __syncthreads();
        sm[t] += a;
        __syncthreads();
    }
    if (i < NN) {
        int rp = boff_s + sm[t] - v;
        rowptr[i] = rp;
        #pragma unroll
        for (int r = 0; r < 8; r++)
            rowbase8[r * NN + i] = rp + (int)repbase[r * NN + i];
    }
    if (i == NN - 1) rowptr[NN] = boff_s + sm[t];
}

// ---- scatter: pos = rowbase8[rep][dst] + rank[e]; ONE random gather, no atomics ----
__global__ void scatter_k(const int* __restrict__ ei, const float* __restrict__ ew,
                          const int* __restrict__ rowbase8,
                          const int* __restrict__ rank, int2* __restrict__ csr) {
    int e = blockIdx.x * 256 + threadIdx.x;
    if (e >= EE) return;
    int src = ei[e];
    int dst = ei[EE + e];
    int rep = (e >> 8) & 7;
    int pos = rowbase8[rep * NN + dst] + rank[e];
    csr[pos] = make_int2(src, __float_as_int(ew[e]));
}

// ---------------- GEMM2 (MFMA fp16, z1 fp16 in) + fused attvec2; h2 fp16 ----------------
__global__ __launch_bounds__(256) void gemm2_k(const __half* __restrict__ z1,
                                               const float* __restrict__ W,
                                               const float* __restrict__ attS,
                                               const float* __restrict__ attD,
                                               __half* __restrict__ h2,
                                               float* __restrict__ asrc,
                                               float* __restrict__ adst) {
    __shared__ __align__(16) _Float16 xs[64 * 136];
    int rowbase = blockIdx.x * 64;
    int t = threadIdx.x;
    int wid = t >> 6, lane = t & 63;
    #pragma unroll
    for (int i = 0; i < 4; i++) {
        int idx = t + i * 256;
        int r = idx >> 4;
        int c16 = idx & 15;
        uint4 v = make_uint4(0, 0, 0, 0);
        if (rowbase + r < NN) v = ((const uint4*)z1)[(size_t)(rowbase + r) * 16 + c16];
        *(uint4*)&xs[r * 136 + c16 * 8] = v;
    }
    half8v bf[2][4];
    #pragma unroll
    for (int nt = 0; nt < 2; nt++)
        #pragma unroll
        for (int kk = 0; kk < 4; kk++) {
            int kb = kk * 32 + ((lane >> 4) << 3);
            int c = (nt << 4) + (lane & 15);
            half8v f;
            #pragma unroll
            for (int j = 0; j < 8; j++) f[j] = (_Float16)W[(kb + j) * 32 + c];
            bf[nt][kk] = f;
        }
    __syncthreads();
    int ar = lane & 15;
    int ak = (lane >> 4) << 3;
    f32x4 acc[2] = {};
    #pragma unroll
    for (int kk = 0; kk < 4; kk++) {
        half8v a = *(const half8v*)&xs[(wid * 16 + ar) * 136 + kk * 32 + ak];
        #pragma unroll
        for (int nt = 0; nt < 2; nt++)
            acc[nt] = __builtin_amdgcn_mfma_f32_16x16x32_f16(a, bf[nt][kk], acc[nt], 0, 0, 0);
    }
    __syncthreads();
    int drb = (lane >> 4) << 2;
    #pragma unroll
    for (int nt = 0; nt < 2; nt++)
        #pragma unroll
        for (int r = 0; r < 4; r++)
            xs[(wid * 16 + drb + r) * 40 + (nt << 4) + (lane & 15)] = (_Float16)acc[nt][r];
    __syncthreads();
    int row = t >> 2;
    int c8 = (t & 3) * 8;
    int grow = rowbase + row;
    half8v hv = *(const half8v*)&xs[row * 40 + c8];
    if (grow < NN) *(half8v*)((_Float16*)h2 + (size_t)grow * 32 + c8) = hv;
    float sv = 0.f, dv = 0.f;
    #pragma unroll
    for (int j = 0; j < 8; j++) {
        float f = (float)hv[j];
        sv += f * attS[c8 + j];
        dv += f * attD[c8 + j];
    }
    sv += __shfl_xor(sv, 1);
    dv += __shfl_xor(dv, 1);
    sv += __shfl_xor(sv, 2);
    dv += __shfl_xor(dv, 2);
    if ((t & 3) == 0 && grow < NN) { asrc[grow] = sv; adst[grow] = dv; }
}

// ---------------- layer1 aggregation (loopa computed in-kernel from sumw) ----------------
__global__ __launch_bounds__(256) void agg1_k(const int* __restrict__ rowptr,
                       const int2* __restrict__ csr,
                       const __half* __restrict__ h1, const float* __restrict__ asrc,
                       const float* __restrict__ adst, const float* __restrict__ cE,
                       const float* __restrict__ b1, __half* __restrict__ z1) {
    __shared__ int    ssrc[4][128];
    __shared__ float2 sxx[4][128];
    __shared__ int2   spk[4][136];
    int wid = threadIdx.x >> 6;
    int n = (blockIdx.x * blockDim.x + threadIdx.x) >> 6;
    int lane = threadIdx.x & 63;
    if (n >= NN) return;
    int start = rowptr[n];
    int degn = rowptr[n + 1] - start;
    int total = degn + 1;
    float c0 = cE[0], c1 = cE[1];
    float ad0 = adst[n * 2], ad1 = adst[n * 2 + 1];
    float s0 = 0.f, s1 = 0.f, sumw = 0.f;
    for (int i = lane; i < degn; i += 64) {
        int2 sw = csr[start + i];
        int src = sw.x;
        float w = __int_as_float(sw.y);
        sumw += w;
        float2 as = *(const float2*)&asrc[src * 2];
        float e0 = as.x + ad0 + w * c0; e0 = e0 > 0.f ? e0 : 0.2f * e0;
        float e1 = as.y + ad1 + w * c1; e1 = e1 > 0.f ? e1 : 0.2f * e1;
        float x0 = __expf(e0), x1 = __expf(e1);
        s0 += x0; s1 += x1;
        if (i < 128) { ssrc[wid][i] = src; sxx[wid][i] = make_float2(x0, x1); }
    }
    for (int off = 32; off; off >>= 1) {
        s0 += __shfl_xor(s0, off);
        s1 += __shfl_xor(s1, off);
        sumw += __shfl_xor(sumw, off);
    }
    float la = sumw / fmaxf((float)degn, 1.0f);
    float2 asn = *(const float2*)&asrc[n * 2];
    float el0 = asn.x + ad0 + la * c0; el0 = el0 > 0.f ? el0 : 0.2f * el0;
    float el1 = asn.y + ad1 + la * c1; el1 = el1 > 0.f ? el1 : 0.2f * el1;
    float xl0 = __expf(el0), xl1 = __expf(el1);
    s0 += xl0; s1 += xl1;
    if (degn < 128 && lane == (degn & 63)) {
        ssrc[wid][degn] = n;
        sxx[wid][degn] = make_float2(xl0, xl1);
    }
    float inv0 = 1.0f / (s0 + 1e-16f), inv1 = 1.0f / (s1 + 1e-16f);
    int nst = min(total, 128);
    int nst8 = (nst + 7) & ~7;
    for (int i = lane; i < nst8; i += 64) {
        int2 pk;
        if (i < nst) {
            float2 xv = sxx[wid][i];
            __half2 hh = __floats2half2_rn(xv.x * inv0, xv.y * inv1);
            pk = make_int2(ssrc[wid][i], *(int*)&hh);
        } else pk = make_int2(n, 0);
        spk[wid][i] = pk;
    }
    int hsel = lane >> 5;
    unsigned psel = hsel ? 0x03020302u : 0x01000100u;
    unsigned loff = (unsigned)lane * 4u;
    const char* h1b_ = (const char*)h1;
    float acc0 = 0.f, acc1 = 0.f;
    for (int j = 0; j < nst8; j += 8) {
        h2v pa = {}, pb = {};
        #pragma unroll
        for (int u = 0; u < 8; u++) {
            int2 st = spk[wid][j + u];
            unsigned cs = __builtin_amdgcn_perm(0u, (unsigned)st.y, psel);
            unsigned hb = *(const unsigned*)(h1b_ + (((unsigned)st.x << 8) + loff));
            h2v c; __builtin_memcpy(&c, &cs, 4);
            h2v h; __builtin_memcpy(&h, &hb, 4);
            if (u & 1) pb = c * h + pb;
            else       pa = c * h + pa;
        }
        acc0 += (float)pa.x + (float)pb.x;
        acc1 += (float)pa.y + (float)pb.y;
    }
    for (int base = 128; base < total; base += 64) {
        int i = base + lane;
        float cc0 = 0.f, cc1 = 0.f; int src = n;
        if (i < total) {
            float w;
            if (i < degn) { int2 sw = csr[start + i]; src = sw.x; w = __int_as_float(sw.y); }
            else          { w = la; }
            float e0 = asrc[src * 2]     + ad0 + w * c0; e0 = e0 > 0.f ? e0 : 0.2f * e0;
            float e1 = asrc[src * 2 + 1] + ad1 + w * c1; e1 = e1 > 0.f ? e1 : 0.2f * e1;
            cc0 = __expf(e0) * inv0;
            cc1 = __expf(e1) * inv1;
        }
        int cnt = min(64, total - base);
        for (int jj = 0; jj < cnt; jj++) {
            int   s2 = __shfl(src, jj);
            float k0 = __shfl(cc0, jj);
            float k1 = __shfl(cc1, jj);
            float coef = hsel ? k1 : k0;
            float2 f = __half22float2(*(const __half2*)&h1[(size_t)s2 * 128 + 2 * lane]);
            acc0 += coef * f.x;
            acc1 += coef * f.y;
        }
    }
    float o0 = acc0 + b1[2 * lane];
    float o1 = acc1 + b1[2 * lane + 1];
    o0 = o0 > 0.f ? o0 : expm1f(o0);
    o1 = o1 > 0.f ? o1 : expm1f(o1);
    __half2 oz = __floats2half2_rn(o0, o1);
    *(__half2*)&z1[(size_t)n * 128 + 2 * lane] = oz;
}

// ---------------- layer2 aggregation (loopa in-kernel) ----------------
__global__ __launch_bounds__(256) void agg2_k(const int* __restrict__ rowptr,
                       const int2* __restrict__ csr,
                       const __half* __restrict__ hh2, const float* __restrict__ asrc,
                       const float* __restrict__ adst, const float* __restrict__ cE,
                       const float* __restrict__ b2, float* __restrict__ out) {
    __shared__ float2 sxx[4][128];
    __shared__ int    ssrc[4][128];
    __shared__ int2   spk[4][136];
    int wid = threadIdx.x >> 6;
    int n = (blockIdx.x * blockDim.x + threadIdx.x) >> 6;
    int lane = threadIdx.x & 63;
    if (n >= NN) return;
    int start = rowptr[n];
    int degn = rowptr[n + 1] - start;
    int total = degn + 1;
    float c2 = cE[2];
    float aD = adst[n];
    float s = 0.f, sumw = 0.f;
    for (int i = lane; i < degn; i += 64) {
        int2 sw = csr[start + i];
        int src = sw.x;
        float w = __int_as_float(sw.y);
        sumw += w;
        float e = asrc[src] + aD + w * c2;
        e = e > 0.f ? e : 0.2f * e;
        float x = __expf(e);
        s += x;
        if (i < 128) { ssrc[wid][i] = src; sxx[wid][i] = make_float2(x, 0.f); }
    }
    for (int off = 32; off; off >>= 1) {
        s += __shfl_xor(s, off);
        sumw += __shfl_xor(sumw, off);
    }
    float la = sumw / fmaxf((float)degn, 1.0f);
    float el = asrc[n] + aD + la * c2; el = el > 0.f ? el : 0.2f * el;
    float xl = __expf(el);
    s += xl;
    if (degn < 128 && lane == (degn & 63)) {
        ssrc[wid][degn] = n;
        sxx[wid][degn] = make_float2(xl, 0.f);
    }
    float inv = 1.0f / (s + 1e-16f);
    int nst = min(total, 128);
    int nst8 = (nst + 7) & ~7;
    for (int i = lane; i < nst8; i += 64) {
        int2 pk;
        if (i < nst) {
            float cn = sxx[wid][i].x * inv;
            __half2 hc = __floats2half2_rn(cn, cn);
            pk = make_int2(ssrc[wid][i], *(int*)&hc);
        } else pk = make_int2(n, 0);
        spk[wid][i] = pk;
    }
    int g  = lane >> 4;
    int cp = lane & 15;
    const char* h2b_ = (const char*)hh2;
    unsigned coff = (unsigned)cp * 4u;
    float fa0 = 0.f, fa1 = 0.f;
    h2v pa = {}, pb = {};
    int fold = 0;
    for (int j = 0; j < nst8; j += 8) {
        int2 st0 = spk[wid][j + g];
        int2 st1 = spk[wid][j + 4 + g];
        unsigned hb0 = *(const unsigned*)(h2b_ + (((unsigned)st0.x << 6) + coff));
        unsigned hb1 = *(const unsigned*)(h2b_ + (((unsigned)st1.x << 6) + coff));
        h2v c0v; __builtin_memcpy(&c0v, &st0.y, 4);
        h2v c1v; __builtin_memcpy(&c1v, &st1.y, 4);
        h2v h0; __builtin_memcpy(&h0, &hb0, 4);
        h2v h1v; __builtin_memcpy(&h1v, &hb1, 4);
        pa = c0v * h0 + pa;
        pb = c1v * h1v + pb;
        if (++fold == 4) {
            fa0 += (float)pa.x + (float)pb.x;
            fa1 += (float)pa.y + (float)pb.y;
            pa = {}; pb = {};
            fold = 0;
        }
    }
    fa0 += (float)pa.x + (float)pb.x;
    fa1 += (float)pa.y + (float)pb.y;
    for (int i = 128; i < total; i++) {
        int src; float w;
        if (i < degn) { int2 sw = csr[start + i]; src = sw.x; w = __int_as_float(sw.y); }
        else          { src = n;                  w = la; }
        float e = asrc[src] + aD + w * c2;
        e = e > 0.f ? e : 0.2f * e;
        float cc = __expf(e) * inv;
        if (g == 0) {
            unsigned hb = *(const unsigned*)(h2b_ + (((unsigned)src << 6) + coff));
            h2v h; __builtin_memcpy(&h, &hb, 4);
            fa0 += cc * (float)h.x;
            fa1 += cc * (float)h.y;
        }
    }
    fa0 += __shfl_xor(fa0, 16); fa1 += __shfl_xor(fa1, 16);
    fa0 += __shfl_xor(fa0, 32); fa1 += __shfl_xor(fa1, 32);
    if (lane < 16) {
        float2 o = make_float2(fa0 + b2[2 * cp], fa1 + b2[2 * cp + 1]);
        *(float2*)&out[(size_t)n * 32 + 2 * cp] = o;
    }
}

extern "C" void kernel_launch(void* const* d_in, const int* in_sizes, int n_in,
                              void* d_out, int out_size, void* d_ws, size_t ws_size,
                              hipStream_t stream) {
    const float* x     = (const float*)d_in[0];
    const int*   ei    = (const int*)d_in[1];
    const float* ew    = (const float*)d_in[2];
    const float* W1    = (const float*)d_in[3];
    const float* attS1 = (const float*)d_in[4];
    const float* attD1 = (const float*)d_in[5];
    const float* We1   = (const float*)d_in[6];
    const float* attE1 = (const float*)d_in[7];
    const float* b1    = (const float*)d_in[8];
    const float* W2    = (const float*)d_in[9];
    const float* attS2 = (const float*)d_in[10];
    const float* attD2 = (const float*)d_in[11];
    const float* We2   = (const float*)d_in[12];
    const float* attE2 = (const float*)d_in[13];
    const float* b2    = (const float*)d_in[14];

    char* ws = (char*)d_ws;
    size_t off = 0;
    auto alloc = [&](size_t bytes) -> void* {
        void* p = ws + off;
        off = (off + bytes + 255) & ~(size_t)255;
        return p;
    };
    unsigned*       dreg     = (unsigned*)alloc((size_t)NN * 8 * 4);
    unsigned short* repbase  = (unsigned short*)alloc((size_t)NN * 8 * 2);
    int*            rowbase8 = (int*)alloc((size_t)NN * 8 * 4);
    int*    rank    = (int*)alloc((size_t)EE * 4);
    int*    deg     = (int*)alloc((size_t)NN * 4);
    int*    rowptr  = (int*)alloc((size_t)(NN + 1) * 4);
    int2*   csr     = (int2*)alloc((size_t)EE * 8);
    __half* h1b     = (__half*)alloc((size_t)NN * 128 * 2);
    __half* z1      = (__half*)alloc((size_t)NN * 128 * 2);
    __half* h2b     = (__half*)alloc((size_t)NN * 32 * 2);
    float*  asrc1   = (float*)alloc((size_t)NN * 2 * 4);
    float*  adst1   = (float*)alloc((size_t)NN * 2 * 4);
    float*  asrc2   = (float*)alloc((size_t)NN * 4);
    float*  adst2   = (float*)alloc((size_t)NN * 4);
    float*  cE      = (float*)alloc(4 * 4);
    int*    bsum    = (int*)alloc(256 * 4);

    const int EB  = (EE + 255) / 256;
    const int NWB = (NN * 64 + 255) / 256;   // one wave per node

    init_k<<<ZB + 1, 256, 0, stream>>>(dreg, We1, attE1, We2, attE2, cE);
    histgemm_k<<<FT, 256, 0, stream>>>(ei, dreg, rank, x, W1, attS1, attD1,
                                       h1b, asrc1, adst1);
    combine_k<<<SB, 256, 0, stream>>>(dreg, deg, repbase, bsum);
    scan_final_k<<<SB, 256, 0, stream>>>(deg, bsum, repbase, rowptr, rowbase8);
    scatter_k<<<EB, 256, 0, stream>>>(ei, ew, rowbase8, rank, csr);

    agg1_k<<<NWB, 256, 0, stream>>>(rowptr, csr, h1b, asrc1, adst1, cE, b1, z1);
    gemm2_k<<<GB, 256, 0, stream>>>(z1, W2, attS2, attD2, h2b, asrc2, adst2);
    agg2_k<<<NWB, 256, 0, stream>>>(rowptr, csr, h2b, asrc2, adst2, cE, b2, (float*)d_out);
}

// Round 12
// 141.543 us; speedup vs baseline: 1.1051x; 1.1051x over previous
//
#include <hip/hip_runtime.h>
#include <hip/hip_bf16.h>
#include <hip/hip_fp16.h>
#include <cstddef>

#define NN 50000
#define EE 800000
#define SB  196    // ceil(NN/256)
#define GB  782    // ceil(NN/64)
#define ZB  1563   // ceil(8*NN/256)

typedef _Float16 half4v __attribute__((ext_vector_type(4)));
typedef _Float16 half8v __attribute__((ext_vector_type(8)));
typedef _Float16 h2v    __attribute__((ext_vector_type(2)));
typedef float    f32x4  __attribute__((ext_vector_type(4)));

// ---- heterogeneous init: [0,ZB) zero dreg | ZB: cE | (ZB,ZB+GB]: gemm1 tiles ----
__global__ __launch_bounds__(256) void initgemm_k(
        unsigned* __restrict__ dreg,
        const float* __restrict__ We1, const float* __restrict__ attE1,
        const float* __restrict__ We2, const float* __restrict__ attE2,
        float* __restrict__ cE,
        const float* __restrict__ x, const float* __restrict__ W,
        const float* __restrict__ attS, const float* __restrict__ attD,
        __half* __restrict__ h1, float* __restrict__ asrc, float* __restrict__ adst) {
    __shared__ __align__(16) _Float16 xs[64 * 136];
    int t = threadIdx.x;
    int b = blockIdx.x;
    if (b < ZB) {
        int i = b * 256 + t;
        if (i < 8 * NN) dreg[i] = 0u;
        return;
    }
    if (b == ZB) {
        float* smc = (float*)xs;
        if (t < 128) smc[t] = We1[t] * attE1[t];
        __syncthreads();
        for (int off = 32; off; off >>= 1) {
            if (t < 128 && (t & 63) < off) smc[t] += smc[t + off];
            __syncthreads();
        }
        if (t == 0)  cE[0] = smc[0];
        if (t == 64) cE[1] = smc[64];
        __syncthreads();
        if (t < 32) smc[t] = We2[t] * attE2[t];
        __syncthreads();
        for (int off = 16; off; off >>= 1) {
            if (t < off) smc[t] += smc[t + off];
            __syncthreads();
        }
        if (t == 0) cE[2] = smc[0];
        return;
    }
    int tile = b - ZB - 1;           // 0..GB-1
    int rowbase = tile * 64;
    int wid = t >> 6, lane = t & 63;
    #pragma unroll
    for (int i = 0; i < 8; i++) {
        int idx = t + i * 256;
        int r = idx >> 5;
        int c4 = idx & 31;
        float4 v = make_float4(0.f, 0.f, 0.f, 0.f);
        if (rowbase + r < NN) v = ((const float4*)x)[(size_t)(rowbase + r) * 32 + c4];
        half4v hv = { (_Float16)v.x, (_Float16)v.y, (_Float16)v.z, (_Float16)v.w };
        *(half4v*)&xs[r * 136 + c4 * 4] = hv;
    }
    half8v bf[2][4];
    #pragma unroll
    for (int nt = 0; nt < 2; nt++)
        #pragma unroll
        for (int kk = 0; kk < 4; kk++) {
            int kb = kk * 32 + ((lane >> 4) << 3);
            int c = (wid << 5) + (nt << 4) + (lane & 15);
            half8v f;
            #pragma unroll
            for (int j = 0; j < 8; j++) f[j] = (_Float16)W[(kb + j) * 128 + c];
            bf[nt][kk] = f;
        }
    __syncthreads();
    int ar = lane & 15;
    int ak = (lane >> 4) << 3;
    f32x4 acc[4][2] = {};
    #pragma unroll
    for (int kk = 0; kk < 4; kk++) {
        half8v a[4];
        #pragma unroll
        for (int mt = 0; mt < 4; mt++)
            a[mt] = *(const half8v*)&xs[(mt * 16 + ar) * 136 + kk * 32 + ak];
        #pragma unroll
        for (int mt = 0; mt < 4; mt++)
            #pragma unroll
            for (int nt = 0; nt < 2; nt++)
                acc[mt][nt] = __builtin_amdgcn_mfma_f32_16x16x32_f16(
                    a[mt], bf[nt][kk], acc[mt][nt], 0, 0, 0);
    }
    __syncthreads();
    int drb = (lane >> 4) << 2;
    int dc = (wid << 5) + (lane & 15);
    #pragma unroll
    for (int mt = 0; mt < 4; mt++)
        #pragma unroll
        for (int nt = 0; nt < 2; nt++)
            #pragma unroll
            for (int r = 0; r < 4; r++)
                xs[(mt * 16 + drb + r) * 136 + dc + nt * 16] = (_Float16)acc[mt][nt][r];
    __syncthreads();
    int row = t >> 2;
    int cg = t & 3;
    int grow = rowbase + row;
    float sv = 0.f, dv = 0.f;
    #pragma unroll
    for (int k = 0; k < 4; k++) {
        int c0 = cg * 32 + k * 8;
        half8v hv = *(const half8v*)&xs[row * 136 + c0];
        if (grow < NN) *(half8v*)((_Float16*)h1 + (size_t)grow * 128 + c0) = hv;
        #pragma unroll
        for (int j = 0; j < 8; j++) {
            float f = (float)hv[j];
            sv += f * attS[c0 + j];
            dv += f * attD[c0 + j];
        }
    }
    sv += __shfl_xor(sv, 1);
    dv += __shfl_xor(dv, 1);
    if ((cg & 1) == 0 && grow < NN) {
        asrc[grow * 2 + (cg >> 1)] = sv;
        adst[grow * 2 + (cg >> 1)] = dv;
    }
}

// ---- hist: u32 atomic into replica (blockIdx&7); returned old = rank in replica ----
__global__ void hist_k(const int* __restrict__ ei, unsigned* __restrict__ dreg,
                       int* __restrict__ rank) {
    int e = blockIdx.x * 256 + threadIdx.x;
    if (e >= EE) return;
    int dst = ei[EE + e];
    int rep = blockIdx.x & 7;
    rank[e] = (int)atomicAdd(&dreg[rep * NN + dst], 1u);
}

// ---- combine replicas -> deg, per-replica base (ushort), block partial sums ----
__global__ void combine_k(const unsigned* __restrict__ dreg, int* __restrict__ deg,
                          unsigned short* __restrict__ repbase, int* __restrict__ bsum) {
    __shared__ int sm[256];
    int t = threadIdx.x, n = blockIdx.x * 256 + t;
    int d = 0;
    if (n < NN) {
        unsigned base = 0;
        #pragma unroll
        for (int r = 0; r < 8; r++) {
            unsigned c = dreg[r * NN + n];
            repbase[r * NN + n] = (unsigned short)base;
            base += c;
        }
        d = (int)base;
        deg[n] = d;
    }
    sm[t] = d;
    __syncthreads();
    for (int off = 128; off; off >>= 1) {
        if (t < off) sm[t] += sm[t + off];
        __syncthreads();
    }
    if (!t) bsum[blockIdx.x] = sm[0];
}

// ---- scan_final + fold repbase into rowbase8 ----
__global__ void scan_final_k(const int* __restrict__ deg, const int* __restrict__ bsum,
                             const unsigned short* __restrict__ repbase,
                             int* __restrict__ rowptr, int* __restrict__ rowbase8) {
    __shared__ int sm[256];
    __shared__ int boff_s;
    int t = threadIdx.x, b = blockIdx.x, i = b * 256 + t;
    int v0 = (t < b) ? bsum[t] : 0;
    sm[t] = v0;
    __syncthreads();
    for (int off = 128; off; off >>= 1) {
        if (t < off) sm[t] += sm[t + off];
        __syncthreads();
    }
    if (!t) boff_s = sm[0];
    __syncthreads();
    int v = (i < NN) ? deg[i] : 0;
    sm[t] = v;
    __syncthreads();
    for (int off = 1; off < 256; off <<= 1) {
        int a = (t >= off) ? sm[t - off] : 0;
        __syncthreads();
        sm[t] += a;
        __syncthreads();
    }
    if (i < NN) {
        int rp = boff_s + sm[t] - v;
        rowptr[i] = rp;
        #pragma unroll
        for (int r = 0; r < 8; r++)
            rowbase8[r * NN + i] = rp + (int)repbase[r * NN + i];
    }
    if (i == NN - 1) rowptr[NN] = boff_s + sm[t];
}

// ---- scatter: pos = rowbase8[rep][dst] + rank[e]; one random gather, no atomics ----
__global__ void scatter_k(const int* __restrict__ ei, const float* __restrict__ ew,
                          const int* __restrict__ rowbase8,
                          const int* __restrict__ rank, int2* __restrict__ csr) {
    int e = blockIdx.x * 256 + threadIdx.x;
    if (e >= EE) return;
    int src = ei[e];
    int dst = ei[EE + e];
    int rep = (e >> 8) & 7;
    int pos = rowbase8[rep * NN + dst] + rank[e];
    csr[pos] = make_int2(src, __float_as_int(ew[e]));
}

// ---------------- GEMM2 (MFMA fp16, z1 fp16 in) + fused attvec2; h2 fp16 ----------------
__global__ __launch_bounds__(256) void gemm2_k(const __half* __restrict__ z1,
                                               const float* __restrict__ W,
                                               const float* __restrict__ attS,
                                               const float* __restrict__ attD,
                                               __half* __restrict__ h2,
                                               float* __restrict__ asrc,
                                               float* __restrict__ adst) {
    __shared__ __align__(16) _Float16 xs[64 * 136];
    int rowbase = blockIdx.x * 64;
    int t = threadIdx.x;
    int wid = t >> 6, lane = t & 63;
    #pragma unroll
    for (int i = 0; i < 4; i++) {
        int idx = t + i * 256;
        int r = idx >> 4;
        int c16 = idx & 15;
        uint4 v = make_uint4(0, 0, 0, 0);
        if (rowbase + r < NN) v = ((const uint4*)z1)[(size_t)(rowbase + r) * 16 + c16];
        *(uint4*)&xs[r * 136 + c16 * 8] = v;
    }
    half8v bf[2][4];
    #pragma unroll
    for (int nt = 0; nt < 2; nt++)
        #pragma unroll
        for (int kk = 0; kk < 4; kk++) {
            int kb = kk * 32 + ((lane >> 4) << 3);
            int c = (nt << 4) + (lane & 15);
            half8v f;
            #pragma unroll
            for (int j = 0; j < 8; j++) f[j] = (_Float16)W[(kb + j) * 32 + c];
            bf[nt][kk] = f;
        }
    __syncthreads();
    int ar = lane & 15;
    int ak = (lane >> 4) << 3;
    f32x4 acc[2] = {};
    #pragma unroll
    for (int kk = 0; kk < 4; kk++) {
        half8v a = *(const half8v*)&xs[(wid * 16 + ar) * 136 + kk * 32 + ak];
        #pragma unroll
        for (int nt = 0; nt < 2; nt++)
            acc[nt] = __builtin_amdgcn_mfma_f32_16x16x32_f16(a, bf[nt][kk], acc[nt], 0, 0, 0);
    }
    __syncthreads();
    int drb = (lane >> 4) << 2;
    #pragma unroll
    for (int nt = 0; nt < 2; nt++)
        #pragma unroll
        for (int r = 0; r < 4; r++)
            xs[(wid * 16 + drb + r) * 40 + (nt << 4) + (lane & 15)] = (_Float16)acc[nt][r];
    __syncthreads();
    int row = t >> 2;
    int c8 = (t & 3) * 8;
    int grow = rowbase + row;
    half8v hv = *(const half8v*)&xs[row * 40 + c8];
    if (grow < NN) *(half8v*)((_Float16*)h2 + (size_t)grow * 32 + c8) = hv;
    float sv = 0.f, dv = 0.f;
    #pragma unroll
    for (int j = 0; j < 8; j++) {
        float f = (float)hv[j];
        sv += f * attS[c8 + j];
        dv += f * attD[c8 + j];
    }
    sv += __shfl_xor(sv, 1);
    dv += __shfl_xor(dv, 1);
    sv += __shfl_xor(sv, 2);
    dv += __shfl_xor(dv, 2);
    if ((t & 3) == 0 && grow < NN) { asrc[grow] = sv; adst[grow] = dv; }
}

// ---------------- layer1 aggregation (loopa computed in-kernel from sumw) ----------------
__global__ __launch_bounds__(256) void agg1_k(const int* __restrict__ rowptr,
                       const int2* __restrict__ csr,
                       const __half* __restrict__ h1, const float* __restrict__ asrc,
                       const float* __restrict__ adst, const float* __restrict__ cE,
                       const float* __restrict__ b1, __half* __restrict__ z1) {
    __shared__ int    ssrc[4][128];
    __shared__ float2 sxx[4][128];
    __shared__ int2   spk[4][136];
    int wid = threadIdx.x >> 6;
    int n = (blockIdx.x * blockDim.x + threadIdx.x) >> 6;
    int lane = threadIdx.x & 63;
    if (n >= NN) return;
    int start = rowptr[n];
    int degn = rowptr[n + 1] - start;
    int total = degn + 1;
    float c0 = cE[0], c1 = cE[1];
    float ad0 = adst[n * 2], ad1 = adst[n * 2 + 1];
    float s0 = 0.f, s1 = 0.f, sumw = 0.f;
    for (int i = lane; i < degn; i += 64) {
        int2 sw = csr[start + i];
        int src = sw.x;
        float w = __int_as_float(sw.y);
        sumw += w;
        float2 as = *(const float2*)&asrc[src * 2];
        float e0 = as.x + ad0 + w * c0; e0 = e0 > 0.f ? e0 : 0.2f * e0;
        float e1 = as.y + ad1 + w * c1; e1 = e1 > 0.f ? e1 : 0.2f * e1;
        float x0 = __expf(e0), x1 = __expf(e1);
        s0 += x0; s1 += x1;
        if (i < 128) { ssrc[wid][i] = src; sxx[wid][i] = make_float2(x0, x1); }
    }
    for (int off = 32; off; off >>= 1) {
        s0 += __shfl_xor(s0, off);
        s1 += __shfl_xor(s1, off);
        sumw += __shfl_xor(sumw, off);
    }
    float la = sumw / fmaxf((float)degn, 1.0f);
    float2 asn = *(const float2*)&asrc[n * 2];
    float el0 = asn.x + ad0 + la * c0; el0 = el0 > 0.f ? el0 : 0.2f * el0;
    float el1 = asn.y + ad1 + la * c1; el1 = el1 > 0.f ? el1 : 0.2f * el1;
    float xl0 = __expf(el0), xl1 = __expf(el1);
    s0 += xl0; s1 += xl1;
    if (degn < 128 && lane == (degn & 63)) {
        ssrc[wid][degn] = n;
        sxx[wid][degn] = make_float2(xl0, xl1);
    }
    float inv0 = 1.0f / (s0 + 1e-16f), inv1 = 1.0f / (s1 + 1e-16f);
    int nst = min(total, 128);
    int nst8 = (nst + 7) & ~7;
    for (int i = lane; i < nst8; i += 64) {
        int2 pk;
        if (i < nst) {
            float2 xv = sxx[wid][i];
            __half2 hh = __floats2half2_rn(xv.x * inv0, xv.y * inv1);
            pk = make_int2(ssrc[wid][i], *(int*)&hh);
        } else pk = make_int2(n, 0);
        spk[wid][i] = pk;
    }
    int hsel = lane >> 5;
    unsigned psel = hsel ? 0x03020302u : 0x01000100u;
    unsigned loff = (unsigned)lane * 4u;
    const char* h1b_ = (const char*)h1;
    float acc0 = 0.f, acc1 = 0.f;
    for (int j = 0; j < nst8; j += 8) {
        h2v pa = {}, pb = {};
        #pragma unroll
        for (int u = 0; u < 8; u++) {
            int2 st = spk[wid][j + u];
            unsigned cs = __builtin_amdgcn_perm(0u, (unsigned)st.y, psel);
            unsigned hb = *(const unsigned*)(h1b_ + (((unsigned)st.x << 8) + loff));
            h2v c; __builtin_memcpy(&c, &cs, 4);
            h2v h; __builtin_memcpy(&h, &hb, 4);
            if (u & 1) pb = c * h + pb;
            else       pa = c * h + pa;
        }
        acc0 += (float)pa.x + (float)pb.x;
        acc1 += (float)pa.y + (float)pb.y;
    }
    for (int base = 128; base < total; base += 64) {
        int i = base + lane;
        float cc0 = 0.f, cc1 = 0.f; int src = n;
        if (i < total) {
            float w;
            if (i < degn) { int2 sw = csr[start + i]; src = sw.x; w = __int_as_float(sw.y); }
            else          { w = la; }
            float e0 = asrc[src * 2]     + ad0 + w * c0; e0 = e0 > 0.f ? e0 : 0.2f * e0;
            float e1 = asrc[src * 2 + 1] + ad1 + w * c1; e1 = e1 > 0.f ? e1 : 0.2f * e1;
            cc0 = __expf(e0) * inv0;
            cc1 = __expf(e1) * inv1;
        }
        int cnt = min(64, total - base);
        for (int jj = 0; jj < cnt; jj++) {
            int   s2 = __shfl(src, jj);
            float k0 = __shfl(cc0, jj);
            float k1 = __shfl(cc1, jj);
            float coef = hsel ? k1 : k0;
            float2 f = __half22float2(*(const __half2*)&h1[(size_t)s2 * 128 + 2 * lane]);
            acc0 += coef * f.x;
            acc1 += coef * f.y;
        }
    }
    float o0 = acc0 + b1[2 * lane];
    float o1 = acc1 + b1[2 * lane + 1];
    o0 = o0 > 0.f ? o0 : expm1f(o0);
    o1 = o1 > 0.f ? o1 : expm1f(o1);
    __half2 oz = __floats2half2_rn(o0, o1);
    *(__half2*)&z1[(size_t)n * 128 + 2 * lane] = oz;
}

// ---------------- layer2 aggregation (loopa in-kernel) ----------------
__global__ __launch_bounds__(256) void agg2_k(const int* __restrict__ rowptr,
                       const int2* __restrict__ csr,
                       const __half* __restrict__ hh2, const float* __restrict__ asrc,
                       const float* __restrict__ adst, const float* __restrict__ cE,
                       const float* __restrict__ b2, float* __restrict__ out) {
    __shared__ float2 sxx[4][128];
    __shared__ int    ssrc[4][128];
    __shared__ int2   spk[4][136];
    int wid = threadIdx.x >> 6;
    int n = (blockIdx.x * blockDim.x + threadIdx.x) >> 6;
    int lane = threadIdx.x & 63;
    if (n >= NN) return;
    int start = rowptr[n];
    int degn = rowptr[n + 1] - start;
    int total = degn + 1;
    float c2 = cE[2];
    float aD = adst[n];
    float s = 0.f, sumw = 0.f;
    for (int i = lane; i < degn; i += 64) {
        int2 sw = csr[start + i];
        int src = sw.x;
        float w = __int_as_float(sw.y);
        sumw += w;
        float e = asrc[src] + aD + w * c2;
        e = e > 0.f ? e : 0.2f * e;
        float x = __expf(e);
        s += x;
        if (i < 128) { ssrc[wid][i] = src; sxx[wid][i] = make_float2(x, 0.f); }
    }
    for (int off = 32; off; off >>= 1) {
        s += __shfl_xor(s, off);
        sumw += __shfl_xor(sumw, off);
    }
    float la = sumw / fmaxf((float)degn, 1.0f);
    float el = asrc[n] + aD + la * c2; el = el > 0.f ? el : 0.2f * el;
    float xl = __expf(el);
    s += xl;
    if (degn < 128 && lane == (degn & 63)) {
        ssrc[wid][degn] = n;
        sxx[wid][degn] = make_float2(xl, 0.f);
    }
    float inv = 1.0f / (s + 1e-16f);
    int nst = min(total, 128);
    int nst8 = (nst + 7) & ~7;
    for (int i = lane; i < nst8; i += 64) {
        int2 pk;
        if (i < nst) {
            float cn = sxx[wid][i].x * inv;
            __half2 hc = __floats2half2_rn(cn, cn);
            pk = make_int2(ssrc[wid][i], *(int*)&hc);
        } else pk = make_int2(n, 0);
        spk[wid][i] = pk;
    }
    int g  = lane >> 4;
    int cp = lane & 15;
    const char* h2b_ = (const char*)hh2;
    unsigned coff = (unsigned)cp * 4u;
    float fa0 = 0.f, fa1 = 0.f;
    h2v pa = {}, pb = {};
    int fold = 0;
    for (int j = 0; j < nst8; j += 8) {
        int2 st0 = spk[wid][j + g];
        int2 st1 = spk[wid][j + 4 + g];
        unsigned hb0 = *(const unsigned*)(h2b_ + (((unsigned)st0.x << 6) + coff));
        unsigned hb1 = *(const unsigned*)(h2b_ + (((unsigned)st1.x << 6) + coff));
        h2v c0v; __builtin_memcpy(&c0v, &st0.y, 4);
        h2v c1v; __builtin_memcpy(&c1v, &st1.y, 4);
        h2v h0; __builtin_memcpy(&h0, &hb0, 4);
        h2v h1v; __builtin_memcpy(&h1v, &hb1, 4);
        pa = c0v * h0 + pa;
        pb = c1v * h1v + pb;
        if (++fold == 4) {
            fa0 += (float)pa.x + (float)pb.x;
            fa1 += (float)pa.y + (float)pb.y;
            pa = {}; pb = {};
            fold = 0;
        }
    }
    fa0 += (float)pa.x + (float)pb.x;
    fa1 += (float)pa.y + (float)pb.y;
    for (int i = 128; i < total; i++) {
        int src; float w;
        if (i < degn) { int2 sw = csr[start + i]; src = sw.x; w = __int_as_float(sw.y); }
        else          { src = n;                  w = la; }
        float e = asrc[src] + aD + w * c2;
        e = e > 0.f ? e : 0.2f * e;
        float cc = __expf(e) * inv;
        if (g == 0) {
            unsigned hb = *(const unsigned*)(h2b_ + (((unsigned)src << 6) + coff));
            h2v h; __builtin_memcpy(&h, &hb, 4);
            fa0 += cc * (float)h.x;
            fa1 += cc * (float)h.y;
        }
    }
    fa0 += __shfl_xor(fa0, 16); fa1 += __shfl_xor(fa1, 16);
    fa0 += __shfl_xor(fa0, 32); fa1 += __shfl_xor(fa1, 32);
    if (lane < 16) {
        float2 o = make_float2(fa0 + b2[2 * cp], fa1 + b2[2 * cp + 1]);
        *(float2*)&out[(size_t)n * 32 + 2 * cp] = o;
    }
}

extern "C" void kernel_launch(void* const* d_in, const int* in_sizes, int n_in,
                              void* d_out, int out_size, void* d_ws, size_t ws_size,
                              hipStream_t stream) {
    const float* x     = (const float*)d_in[0];
    const int*   ei    = (const int*)d_in[1];
    const float* ew    = (const float*)d_in[2];
    const float* W1    = (const float*)d_in[3];
    const float* attS1 = (const float*)d_in[4];
    const float* attD1 = (const float*)d_in[5];
    const float* We1   = (const float*)d_in[6];
    const float* attE1 = (const float*)d_in[7];
    const float* b1    = (const float*)d_in[8];
    const float* W2    = (const float*)d_in[9];
    const float* attS2 = (const float*)d_in[10];
    const float* attD2 = (const float*)d_in[11];
    const float* We2   = (const float*)d_in[12];
    const float* attE2 = (const float*)d_in[13];
    const float* b2    = (const float*)d_in[14];

    char* ws = (char*)d_ws;
    size_t off = 0;
    auto alloc = [&](size_t bytes) -> void* {
        void* p = ws + off;
        off = (off + bytes + 255) & ~(size_t)255;
        return p;
    };
    unsigned*       dreg     = (unsigned*)alloc((size_t)NN * 8 * 4);
    unsigned short* repbase  = (unsigned short*)alloc((size_t)NN * 8 * 2);
    int*            rowbase8 = (int*)alloc((size_t)NN * 8 * 4);
    int*    rank    = (int*)alloc((size_t)EE * 4);
    int*    deg     = (int*)alloc((size_t)NN * 4);
    int*    rowptr  = (int*)alloc((size_t)(NN + 1) * 4);
    int2*   csr     = (int2*)alloc((size_t)EE * 8);
    __half* h1b     = (__half*)alloc((size_t)NN * 128 * 2);
    __half* z1      = (__half*)alloc((size_t)NN * 128 * 2);
    __half* h2b     = (__half*)alloc((size_t)NN * 32 * 2);
    float*  asrc1   = (float*)alloc((size_t)NN * 2 * 4);
    float*  adst1   = (float*)alloc((size_t)NN * 2 * 4);
    float*  asrc2   = (float*)alloc((size_t)NN * 4);
    float*  adst2   = (float*)alloc((size_t)NN * 4);
    float*  cE      = (float*)alloc(4 * 4);
    int*    bsum    = (int*)alloc(256 * 4);

    const int EB  = (EE + 255) / 256;
    const int NWB = (NN * 64 + 255) / 256;   // one wave per node

    initgemm_k<<<ZB + 1 + GB, 256, 0, stream>>>(dreg, We1, attE1, We2, attE2, cE,
                                                x, W1, attS1, attD1, h1b, asrc1, adst1);
    hist_k<<<EB, 256, 0, stream>>>(ei, dreg, rank);
    combine_k<<<SB, 256, 0, stream>>>(dreg, deg, repbase, bsum);
    scan_final_k<<<SB, 256, 0, stream>>>(deg, bsum, repbase, rowptr, rowbase8);
    scatter_k<<<EB, 256, 0, stream>>>(ei, ew, rowbase8, rank, csr);

    agg1_k<<<NWB, 256, 0, stream>>>(rowptr, csr, h1b, asrc1, adst1, cE, b1, z1);
    gemm2_k<<<GB, 256, 0, stream>>>(z1, W2, attS2, attD2, h2b, asrc2, adst2);
    agg2_k<<<NWB, 256, 0, stream>>>(rowptr, csr, h2b, asrc2, adst2, cE, b2, (float*)d_out);
}